// Round 7
// baseline (109.419 us; speedup 1.0000x reference)
//
#include <hip/hip_runtime.h>
#include <cstdint>
#include <cstddef>

typedef unsigned short u16;
typedef __attribute__((ext_vector_type(8))) short short8;
typedef __attribute__((ext_vector_type(4))) float f32x4;

#define CIN   512
#define COUT  512
#define BATCH 16
#define HWSZ  1024      // 32*32
#define PADW  34        // 32 + 2 halo

static constexpr float MOD_SCALE  = 0.044194173824159216f;   // 1/sqrt(512)
static constexpr float CONV_SCALE = 0.014731391274719739f;   // 1/sqrt(512*9)

// workspace layout (bytes)
#define WS_S    0                              // 8192 f32   (32 KB)
#define WS_DSC  (32*1024)                      // 8192 f32   (32 KB)
#define WS_WSQ  (64*1024)                      // 262144 f32 (1 MB)
#define WS_WBT  (64*1024 + 1024*1024)          // 9*512*512 bf16 (4.5 MB)
#define WS_XSP  (WS_WBT + 9*512*512*2)         // 16*34*34*512 bf16 (~18 MB)

__device__ __forceinline__ u16 f2bf(float f) {
  union { float f; uint32_t u; } v; v.f = f;
  uint32_t r = v.u + 0x7fffu + ((v.u >> 16) & 1u);   // RNE
  return (u16)(r >> 16);
}

__device__ __forceinline__ void gload16(const void* g, void* l) {
  __builtin_amdgcn_global_load_lds(
      (const __attribute__((address_space(1))) void*)g,
      (__attribute__((address_space(3))) void*)l, 16, 0, 0);
}

// ---------------- s[b,i] = mod_scale * style[b,:] . mod_w[i,:] + mod_b[i] ----------------
__global__ void k_style(const float* __restrict__ style, const float* __restrict__ mod_w,
                        const float* __restrict__ mod_b, float* __restrict__ s_out) {
  int gid  = blockIdx.x * blockDim.x + threadIdx.x;
  int w    = gid >> 6, lane = gid & 63;
  int b    = w >> 9, i = w & 511;
  const float4* st = (const float4*)(style + (size_t)b * 512);
  const float4* mw = (const float4*)(mod_w + (size_t)i * 512);
  float4 a0 = st[lane * 2], a1 = st[lane * 2 + 1];
  float4 w0 = mw[lane * 2], w1 = mw[lane * 2 + 1];
  float acc = a0.x*w0.x + a0.y*w0.y + a0.z*w0.z + a0.w*w0.w
            + a1.x*w1.x + a1.y*w1.y + a1.z*w1.z + a1.w*w1.w;
  #pragma unroll
  for (int off = 32; off; off >>= 1) acc += __shfl_xor(acc, off);
  if (lane == 0) s_out[w] = acc * MOD_SCALE + mod_b[i];
}

// ---- fused: wsq[o,i] = sum_k w^2 ; wbt2[((kxy*64 + i/8)*512 + o)*8 + i%8] = bf16(w) ----
__global__ void k_wprep(const float* __restrict__ w, float* __restrict__ wsq,
                        u16* __restrict__ wbt2) {
  int idx = blockIdx.x * 256 + threadIdx.x;          // 262144 = o*512+i
  int o = idx >> 9, i = idx & 511;
  const float* p = w + (size_t)idx * 9;
  float a = 0.f;
  #pragma unroll
  for (int kxy = 0; kxy < 9; ++kxy) {
    float v = p[kxy];
    a += v * v;
    wbt2[((size_t)(kxy * 64 + (i >> 3)) * 512 + o) * 8 + (i & 7)] = f2bf(v);
  }
  wsq[idx] = a;
}

// ---------------- dscale[b,o] = conv_scale * rsqrt(cs^2 * sum_i wsq[o,i]*s[b,i]^2 + 1e-8) ----
__global__ void k_dscale(const float* __restrict__ wsq, const float* __restrict__ s,
                         float* __restrict__ dsc) {
  int gid  = blockIdx.x * blockDim.x + threadIdx.x;
  int w    = gid >> 6, lane = gid & 63;
  int b    = w >> 9, o = w & 511;
  const float4* q4 = (const float4*)(wsq + (size_t)o * 512);
  const float4* s4 = (const float4*)(s   + (size_t)b * 512);
  float4 q0 = q4[lane * 2], q1 = q4[lane * 2 + 1];
  float4 t0 = s4[lane * 2], t1 = s4[lane * 2 + 1];
  float acc = q0.x*t0.x*t0.x + q0.y*t0.y*t0.y + q0.z*t0.z*t0.z + q0.w*t0.w*t0.w
            + q1.x*t1.x*t1.x + q1.y*t1.y*t1.y + q1.z*t1.z*t1.z + q1.w*t1.w*t1.w;
  #pragma unroll
  for (int off = 32; off; off >>= 1) acc += __shfl_xor(acc, off);
  if (lane == 0)
    dsc[w] = CONV_SCALE * rsqrtf(acc * CONV_SCALE * CONV_SCALE + 1e-8f);
}

// ---------------- zero only the halo border of xs_p ----------------
__global__ void k_halo(u16* __restrict__ xsp) {
  int cell = blockIdx.x;      // 0..131 border cells of the 34x34 grid
  int b = blockIdx.y;
  int y, x;
  if (cell < 34)       { y = 0;          x = cell; }
  else if (cell < 68)  { y = 33;         x = cell - 34; }
  else if (cell < 100) { y = cell - 67;  x = 0; }    // 1..32
  else                 { y = cell - 99;  x = 33; }   // 1..32
  uint32_t* p = (uint32_t*)(xsp + ((size_t)(b * PADW + y) * PADW + x) * 512);
  p[threadIdx.x] = 0;   // 256 threads x 4B = 512 u16
}

// ---------------- xs_p[b][y+1][x+1][i] = bf16(x[b][i][y][x] * s[b][i])  (NCHW->NHWC) --------
__global__ void k_xs(const float* __restrict__ x, const float* __restrict__ s,
                     u16* __restrict__ xsp) {
  __shared__ float tile[64][33];
  int icb = blockIdx.x, y = blockIdx.y, b = blockIdx.z;
  int t = threadIdx.x;
  int i0 = icb * 64;
  int c  = t & 31;       // x coord
  int r0 = t >> 5;       // 0..7
  #pragma unroll
  for (int it = 0; it < 8; ++it) {
    int row = r0 + it * 8;                           // i_loc 0..63
    float sv = s[b * 512 + i0 + row];
    tile[row][c] = x[((size_t)(b * 512 + i0 + row)) * 1024 + y * 32 + c] * sv;
  }
  __syncthreads();
  int il = t & 63;
  int x0 = t >> 6;       // 0..3
  #pragma unroll
  for (int it = 0; it < 8; ++it) {
    int xc = x0 + it * 4;
    xsp[((size_t)((b * PADW + y + 1) * PADW) + (xc + 1)) * 512 + i0 + il] = f2bf(tile[il][xc]);
  }
}

// ---------------- implicit-GEMM conv + fused epilogue ----------------
// Tile 256(o) x 128(m), 8 waves (4o x 2m, per-wave 64x64), K=4608 in 72 steps of 64.
// A: global->VGPR direct, double-banked, 1 step ahead (L2-resident weights).
// B: 4-deep LDS ring (T2 swizzled), staged 3 steps ahead via global_load_lds;
//    fragments PRE-READ one step ahead into double-banked VGPRs -> MFMA(ks) is
//    pure-register (no same-step LDS dependency; breaks the phase-lock).
// Per step: vmcnt(10) [drains B(ks+1); leaves B(ks+2)+A(ks) in flight] -> barrier
// -> stage B(ks+3) -> avload(ks+1) -> ds_read bvp(ks+1) -> MFMA(ks) (setprio).
__global__ __launch_bounds__(512, 2) void k_conv(
    const u16* __restrict__ wbt2, const u16* __restrict__ xsp,
    const float* __restrict__ dsc, const float* __restrict__ noise,
    const float* __restrict__ nw, const float* __restrict__ abias,
    float* __restrict__ out)
{
  __shared__ u16 Bld[4 * 8192];    // 4 x 128x64 bf16 = 64 KB (swizzled)

  const int tid  = threadIdx.x;
  const int wave = tid >> 6, lane = tid & 63;

  // T1: XCD swizzle (grid 256 = 8 XCD x 32 contiguous tiles)
  const int bid = blockIdx.x;
  const int swz = (bid & 7) * 32 + (bid >> 3);
  const int o0 = (swz >> 7) << 8;     // 0 or 256
  const int m0 = (swz & 127) << 7;    // 0..16256
  const int b  = m0 >> 10;            // uniform per block

  const int wo = (wave >> 1) * 64;    // o sub-block: 0/64/128/192
  const int wm = (wave & 1) * 64;     // m sub-block: 0/64
  const int lrow = lane & 15;
  const int lk   = (lane >> 4) * 8;
  const int rsw  = (lrow & 7) << 3;   // read-side swizzle (u16 units)

  // A: per-lane global base into wbt2 fragment layout
  const u16* pA = wbt2 + (size_t)(lane >> 4) * 4096 + (size_t)(o0 + wo + lrow) * 8;

  // B staging bases (global_load_lds): row = wave*16+q*8+(lane>>3),
  // swizzled source chunk = (lane&7) ^ (row&7)  [T2]
  const int cc = (((lane & 7) ^ (lane >> 3)) * 8);
  const u16* gB[2]; int lBo[2];
  #pragma unroll
  for (int q = 0; q < 2; ++q) {
    int r = wave * 16 + q * 8 + (lane >> 3);          // 0..127
    int mg = m0 + r;
    int yy = (mg >> 5) & 31, xx = mg & 31;
    gB[q] = xsp + ((size_t)(b * PADW + yy) * PADW + xx) * 512 + cc;
    lBo[q] = (wave * 16 + q * 8) * 64;
  }

  f32x4 acc[4][4];
  #pragma unroll
  for (int i = 0; i < 4; ++i)
    #pragma unroll
    for (int j = 0; j < 4; ++j) acc[i][j] = (f32x4){0.f, 0.f, 0.f, 0.f};

  short8 av0[2][4], av1[2][4];   // double-banked A fragments (64 VGPR)
  short8 bv0[2][4], bv1[2][4];   // double-banked B fragments (64 VGPR)

  auto avload = [&](int ks, short8 (&dst)[2][4]) {
    const u16* base = pA + (size_t)(ks >> 3) * 262144 + (size_t)(ks & 7) * 32768;
    #pragma unroll
    for (int kh = 0; kh < 2; ++kh)
      #pragma unroll
      for (int mi = 0; mi < 4; ++mi)
        dst[kh][mi] = *(const short8*)(base + kh * 16384 + mi * 128);
  };

  auto stageB = [&](int ks, int bufi) {
    int kxy = ks >> 3, ib = (ks & 7) << 6;
    int ky = kxy / 3, kx = kxy - ky * 3;
    int offB = ((ky * PADW + kx) << 9) + ib;
    int sb = bufi * 8192;
    #pragma unroll
    for (int q = 0; q < 2; ++q) gload16(gB[q] + offB, &Bld[sb + lBo[q]]);
  };

  auto bvread = [&](int bufi, short8 (&dst)[2][4]) {
    const int cb = bufi * 8192;
    #pragma unroll
    for (int kh = 0; kh < 2; ++kh) {
      int kos = (kh * 32 + lk) ^ rsw;
      #pragma unroll
      for (int ni = 0; ni < 4; ++ni)
        dst[kh][ni] = *(const short8*)&Bld[cb + (wm + ni * 16 + lrow) * 64 + kos];
    }
  };

  auto compute = [&](const short8 (&av)[2][4], const short8 (&bv)[2][4]) {
    __builtin_amdgcn_s_setprio(1);
    #pragma unroll
    for (int kh = 0; kh < 2; ++kh)
      #pragma unroll
      for (int mi = 0; mi < 4; ++mi)
        #pragma unroll
        for (int ni = 0; ni < 4; ++ni)
          acc[mi][ni] = __builtin_amdgcn_mfma_f32_16x16x32_bf16(
              av[kh][mi], bv[kh][ni], acc[mi][ni], 0, 0, 0);
    __builtin_amdgcn_s_setprio(0);
  };

  // prologue: B(0..2) staged, A(0) in flight; drain B(0); pre-read bv0
  stageB(0, 0);
  stageB(1, 1);
  stageB(2, 2);
  avload(0, av0);
  asm volatile("s_waitcnt vmcnt(12)" ::: "memory");   // drain B(0); B1,B2,A0 in flight
  __builtin_amdgcn_s_barrier();
  __builtin_amdgcn_sched_barrier(0);
  bvread(0, bv0);

  // Step ks: vmcnt(10) [worst-case in-flight {B(ks+1),B(ks+2),A(ks)}=12 ->
  // drains B(ks+1) needed by this step's bvread]; barrier; stage B(ks+3) into
  // ring slot (ks+3)&3 [WAR: last read 4 steps / >=2 barriers ago]; load next
  // A+B fragments into the other bank; MFMA current banks (pure-register).
#define STEP(KS, BSTG, BRD, AVC, AVN, BVC, BVN, DOSTG, DOAV, DOBV)       \
  {                                                                      \
    asm volatile("s_waitcnt vmcnt(10)" ::: "memory");                    \
    __builtin_amdgcn_s_barrier();                                        \
    __builtin_amdgcn_sched_barrier(0);                                   \
    if (DOSTG) stageB((KS) + 3, BSTG);                                   \
    if (DOAV)  avload((KS) + 1, AVN);                                    \
    if (DOBV)  bvread(BRD, BVN);                                         \
    compute(AVC, BVC);                                                   \
  }

  for (int t = 0; t < 17; ++t) {
    const int k0 = t * 4;                    // ks = k0..k0+3, k0+3 <= 67
    STEP(k0 + 0, 3, 1, av0, av1, bv0, bv1, 1, 1, 1);
    STEP(k0 + 1, 0, 2, av1, av0, bv1, bv0, 1, 1, 1);
    STEP(k0 + 2, 1, 3, av0, av1, bv0, bv1, 1, 1, 1);
    STEP(k0 + 3, 2, 0, av1, av0, bv1, bv0, 1, 1, 1);
  }
  // tail ks = 68..71
  STEP(68, 3, 1, av0, av1, bv0, bv1, 1, 1, 1);   // stage B(71) -> buf3
  STEP(69, 0, 2, av1, av0, bv1, bv0, 0, 1, 1);
  STEP(70, 1, 3, av0, av1, bv0, bv1, 0, 1, 1);   // bvread B(71) from buf3
  STEP(71, 2, 0, av1, av0, bv1, bv0, 0, 0, 0);
#undef STEP

  // epilogue: demod*conv_scale, noise, bias, leaky(0.2)*sqrt(2)
  const float nwv = nw[0];
  const int mrow = (lane >> 4) << 2;
  #pragma unroll
  for (int mi = 0; mi < 4; ++mi) {
    #pragma unroll
    for (int ni = 0; ni < 4; ++ni) {
      int mg = m0 + wm + ni * 16 + lrow;
      int hw = mg & 1023;
      float nz = nwv * noise[b * 1024 + hw];
      #pragma unroll
      for (int r = 0; r < 4; ++r) {
        int og = o0 + wo + mi * 16 + mrow + r;
        float v = acc[mi][ni][r] * dsc[b * 512 + og] + nz + abias[og];
        v = (v > 0.f ? v : 0.2f * v) * 1.4142135623730951f;
        out[(size_t)(b * 512 + og) * 1024 + hw] = v;
      }
    }
  }
}

extern "C" void kernel_launch(void* const* d_in, const int* in_sizes, int n_in,
                              void* d_out, int out_size, void* d_ws, size_t ws_size,
                              hipStream_t stream) {
  const float* x      = (const float*)d_in[0];
  const float* style  = (const float*)d_in[1];
  const float* noise  = (const float*)d_in[2];
  const float* weight = (const float*)d_in[3];
  const float* mod_w  = (const float*)d_in[4];
  const float* mod_b  = (const float*)d_in[5];
  const float* nw     = (const float*)d_in[6];
  const float* abias  = (const float*)d_in[7];
  float* out = (float*)d_out;

  char* ws = (char*)d_ws;
  float* s_buf = (float*)(ws + WS_S);
  float* dsc   = (float*)(ws + WS_DSC);
  float* wsq   = (float*)(ws + WS_WSQ);
  u16*   wbt2  = (u16*)(ws + WS_WBT);
  u16*   xsp   = (u16*)(ws + WS_XSP);

  k_halo  <<<dim3(132, 16), 256, 0, stream>>>(xsp);
  k_style <<<2048, 256, 0, stream>>>(style, mod_w, mod_b, s_buf);
  k_wprep <<<1024, 256, 0, stream>>>(weight, wsq, wbt2);
  k_dscale<<<2048, 256, 0, stream>>>(wsq, s_buf, dsc);
  k_xs    <<<dim3(8, 32, 16), 256, 0, stream>>>(x, s_buf, xsp);
  k_conv  <<<256, 512, 0, stream>>>(wbt2, xsp, dsc, noise, nw, abias, out);
}